// Round 13
// baseline (344.411 us; speedup 1.0000x reference)
//
#include <hip/hip_runtime.h>

// Problem: B=2, N=128, C=256, H=8, D=32. Inputs fp32, OUTPUT fp32 (proven R6).
// R13: GEMMs widened to 128x128 tiles (32 MFMAs per barrier-pair, 2x the
// arithmetic intensity per vmcnt-drain). Wt padded to 896 rows -> 7 col
// groups. No prefetch regs (R11's spill trap). Attn = R12 (proven).
typedef unsigned short u16;
typedef __attribute__((ext_vector_type(8))) short bf16x8;   // 8 bf16 MFMA A/B frag
typedef __attribute__((ext_vector_type(4))) float f32x4;    // MFMA C/D frag

#define SCALE 0.17677669529663687f  // 32^-0.5

__device__ __forceinline__ float us2f(u16 u){ return __uint_as_float(((unsigned int)u)<<16); }
__device__ __forceinline__ u16 f2us(float f){
  unsigned int x = __float_as_uint(f);
  x += 0x7fffu + ((x>>16)&1u);   // RNE
  return (u16)(x>>16);
}

// ---------------- LayerNorm: one wave per token (256 ch), float4 loads ----------------
__global__ __launch_bounds__(256) void ln_kernel(const float* __restrict__ e, const float* __restrict__ g,
                                                 const float* __restrict__ bb, u16* __restrict__ eln){
  int t = threadIdx.x;
  int tok = blockIdx.x*4 + (t>>6);
  int lane = t & 63;
  int c0 = lane*4;
  float4 x = *(const float4*)(e + tok*256 + c0);
  float sum = x.x+x.y+x.z+x.w;
  float sq  = x.x*x.x + x.y*x.y + x.z*x.z + x.w*x.w;
  #pragma unroll
  for (int off=32; off>=1; off>>=1){ sum += __shfl_xor(sum, off); sq += __shfl_xor(sq, off); }
  float mu = sum * 0.00390625f;
  float var = sq * 0.00390625f - mu*mu;
  float rstd = rsqrtf(var + 1e-5f);
  float4 gv = *(const float4*)(g + c0);
  float4 bv = *(const float4*)(bb + c0);
  ushort4 o;
  o.x = f2us((x.x-mu)*rstd*gv.x + bv.x);
  o.y = f2us((x.y-mu)*rstd*gv.y + bv.y);
  o.z = f2us((x.z-mu)*rstd*gv.z + bv.z);
  o.w = f2us((x.w-mu)*rstd*gv.w + bv.w);
  *(ushort4*)(eln + tok*256 + c0) = o;
}

// ---------------- prep_all: Wt_in/Wt_out [896][256] (rows 776..895 zero), WOt ----------------
__global__ __launch_bounds__(256) void prep_all(const float* __restrict__ Wi, const float* __restrict__ WEi,
                                                const float* __restrict__ Wo, const float* __restrict__ WEo,
                                                const float* __restrict__ WO,
                                                u16* __restrict__ WtI, u16* __restrict__ WtO,
                                                u16* __restrict__ WOt){
  int idx = blockIdx.x*256 + threadIdx.x;   // 589824 total
  if (idx < 458752){
    int which = idx >= 229376;
    int id2 = which ? idx - 229376 : idx;
    const float* W  = which ? Wo  : Wi;
    const float* WE = which ? WEo : WEi;
    u16* Wt = which ? WtO : WtI;
    int n = id2 >> 8, k = id2 & 255;
    float v;
    if (n < 768){
      int sec = n >> 8, r = n & 255, h = r >> 5, d = r & 31;
      v = W[k*768 + sec*256 + d*8 + h];
    } else if (n < 776) v = WE[k*8 + (n-768)];
    else v = 0.f;
    Wt[id2] = f2us(v);
  } else if (idx < 589824){
    int id2 = idx - 458752;        // WOt[256][512]: k' = pass*256+h*32+d <-> row d*16+pass*8+h
    int n = id2 >> 9, kp = id2 & 511;
    int pass = kp >> 8, h = (kp >> 5) & 7, d = kp & 31;
    int r = d*16 + pass*8 + h;
    WOt[id2] = f2us(WO[r*256 + n]);
  }
}

// ---------------- QKV (+E) GEMM: LDS-tiled 128x128, BK=64, 7 col groups ----------------
__global__ __launch_bounds__(256) void qkv_gemm(const u16* __restrict__ eln, const u16* __restrict__ Wt,
    const float* __restrict__ bqkv, const float* __restrict__ bE, const float* __restrict__ mask,
    u16* __restrict__ Qb, u16* __restrict__ Kb, u16* __restrict__ Vb, u16* __restrict__ biasP,
    int pass){
  __shared__ u16 Asm[128][72];
  __shared__ u16 Bsm[128][72];
  int t = threadIdx.x;
  int g = blockIdx.x >> 8;        // 0..6 col group
  int tmb = blockIdx.x & 255;     // token tile
  int row0 = tmb*128, col0 = g*128;
  int w = t >> 6, lane = t & 63, quad = lane >> 4, l15 = lane & 15;

  f32x4 zero = {0.f,0.f,0.f,0.f};
  f32x4 acc[2][8];
  #pragma unroll
  for (int mt=0; mt<2; ++mt)
    #pragma unroll
    for (int nt=0; nt<8; ++nt) acc[mt][nt] = zero;

  for (int kc=0; kc<4; ++kc){
    #pragma unroll
    for (int i=0; i<4; ++i){
      int idx = i*256 + t, row = idx>>3, seg = idx&7;
      *(uint4*)&Asm[row][seg*8] = *(const uint4*)(eln + (row0+row)*256 + kc*64 + seg*8);
      *(uint4*)&Bsm[row][seg*8] = *(const uint4*)(Wt + (col0+row)*256 + kc*64 + seg*8);
    }
    __syncthreads();
    #pragma unroll
    for (int s=0; s<2; ++s){
      bf16x8 aF[2], bF[8];
      #pragma unroll
      for (int mt=0; mt<2; ++mt) aF[mt] = *(const bf16x8*)&Asm[w*32 + mt*16 + l15][s*32 + quad*8];
      #pragma unroll
      for (int nt=0; nt<8; ++nt) bF[nt] = *(const bf16x8*)&Bsm[nt*16 + l15][s*32 + quad*8];
      #pragma unroll
      for (int mt=0; mt<2; ++mt)
        #pragma unroll
        for (int nt=0; nt<8; ++nt)
          acc[mt][nt] = __builtin_amdgcn_mfma_f32_16x16x32_bf16(aF[mt], bF[nt], acc[mt][nt], 0,0,0);
    }
    __syncthreads();
  }
  #pragma unroll
  for (int mt=0; mt<2; ++mt){
    #pragma unroll
    for (int nt=0; nt<8; ++nt){
      int col = col0 + nt*16 + l15;      // n' (permuted order), 0..895
      #pragma unroll
      for (int rr=0; rr<4; ++rr){
        int tok = row0 + w*32 + mt*16 + quad*4 + rr;
        float v = acc[mt][nt][rr];
        if (col < 768){
          int sec = col >> 8, r = col & 255, h = r >> 5, d = r & 31;
          v += bqkv[sec*256 + d*8 + h];
          int off = tok*256 + r;            // [tok][h][d] directly
          if (sec == 0)      Qb[off] = f2us(v * SCALE);
          else if (sec == 1) Kb[off] = f2us(v);
          else               Vb[off] = f2us(v);
        } else if (col < 776){
          int h = col - 768;
          int bb = tok >> 14, t1 = (tok >> 7) & 127, t2 = tok & 127;
          int tq = pass ? t2 : t1, tk = pass ? t1 : t2;
          float bv2 = v + bE[h] + mask[tok*8 + h];   // mask src == tok*8+h both passes
          biasP[(((bb*8 + h)*128 + tq)*128) + (tk & 15)*8 + (tk >> 4)] = f2us(bv2);
        }
      }
    }
  }
}

// ---------------- MFMA attention: one block per (b,j,h) (R12-proven) ----------------
__global__ __launch_bounds__(256) void attn_mfma(const u16* __restrict__ Qb, const u16* __restrict__ Kb,
    const u16* __restrict__ Vb, const u16* __restrict__ biasP, u16* __restrict__ Va, int pass){
  __shared__ __align__(16) u16 uni[17408];     // union{Qs[128][40]+Ks[128][40], Ps[128][136]}
  __shared__ __align__(16) u16 VsT[32][136];
  typedef u16 row40[40];
  typedef u16 row136[136];
  row40*  Qs = (row40*)uni;
  row40*  Ks = (row40*)(uni + 5120);
  row136* Ps = (row136*)uni;
  int t = threadIdx.x;
  int bx = blockIdx.x;
  int h = bx & 7, j = (bx>>3) & 127, b = bx >> 10;

  #pragma unroll
  for (int it2=0; it2<2; ++it2){
    int idx = it2*256 + t;              // 512 chunks of 8 u16
    int row = idx >> 2, seg = idx & 3;
    int qoff  = ((b*128 + row)*128 + j)*256 + h*32 + seg*8;
    int kvtok = (pass == 0) ? ((b*128 + j)*128 + row) : ((b*128 + row)*128 + j);
    int kvoff = kvtok*256 + h*32 + seg*8;
    *(uint4*)&Qs[row][seg*8] = *(const uint4*)(Qb + qoff);
    *(uint4*)&Ks[row][seg*8] = *(const uint4*)(Kb + kvoff);
    uint4 vv = *(const uint4*)(Vb + kvoff);
    const u16* vp = (const u16*)&vv;
    #pragma unroll
    for (int q=0;q<8;++q) VsT[seg*8+q][row] = vp[q];   // transposed: [d][tok]
  }
  __syncthreads();

  int w = t >> 6, lane = t & 63, quad = lane >> 4, l15 = lane & 15;
  bf16x8 aQ[2];
  #pragma unroll
  for (int it=0; it<2; ++it) aQ[it] = *(const bf16x8*)&Qs[w*32 + it*16 + l15][quad*8];
  f32x4 zero = {0.f,0.f,0.f,0.f};
  f32x4 S[2][8];
  #pragma unroll
  for (int tk=0; tk<8; ++tk){
    bf16x8 bK = *(const bf16x8*)&Ks[tk*16 + l15][quad*8];
    #pragma unroll
    for (int it=0; it<2; ++it)
      S[it][tk] = __builtin_amdgcn_mfma_f32_16x16x32_bf16(aQ[it], bK, zero, 0,0,0);
  }
  __syncthreads();   // Qs/Ks dead before Ps overwrites the union
  const u16* bpP = biasP + ((b*8 + h)*128)*128;
  float inv[2][4];
  #pragma unroll
  for (int it=0; it<2; ++it){
    #pragma unroll
    for (int r=0; r<4; ++r){
      int i = w*32 + it*16 + quad*4 + r;
      uint4 b4 = *(const uint4*)(bpP + i*128 + l15*8);
      const u16* bu = (const u16*)&b4;
      float sv[8];
      #pragma unroll
      for (int tk=0; tk<8; ++tk) sv[tk] = S[it][tk][r] + us2f(bu[tk]);
      float m = sv[0];
      #pragma unroll
      for (int tk=1; tk<8; ++tk) m = fmaxf(m, sv[tk]);
      m = fmaxf(m, __shfl_xor(m,1)); m = fmaxf(m, __shfl_xor(m,2));
      m = fmaxf(m, __shfl_xor(m,4)); m = fmaxf(m, __shfl_xor(m,8));
      float l = 0.f;
      #pragma unroll
      for (int tk=0; tk<8; ++tk){ float p = __expf(sv[tk]-m); sv[tk] = p; l += p; }
      l += __shfl_xor(l,1); l += __shfl_xor(l,2); l += __shfl_xor(l,4); l += __shfl_xor(l,8);
      inv[it][r] = 1.0f / l;
      #pragma unroll
      for (int tk=0; tk<8; ++tk) Ps[i][tk*16 + l15] = f2us(sv[tk]);
    }
  }
  f32x4 O[2][2];
  #pragma unroll
  for (int it=0; it<2; ++it)
    #pragma unroll
    for (int dt=0; dt<2; ++dt) O[it][dt] = zero;
  #pragma unroll
  for (int kc=0; kc<4; ++kc){
    bf16x8 bV[2];
    #pragma unroll
    for (int dt=0; dt<2; ++dt)
      bV[dt] = *(const bf16x8*)&VsT[dt*16 + l15][kc*32 + quad*8];
    #pragma unroll
    for (int it=0; it<2; ++it){
      bf16x8 aP = *(const bf16x8*)&Ps[w*32 + it*16 + l15][kc*32 + quad*8];
      #pragma unroll
      for (int dt=0; dt<2; ++dt)
        O[it][dt] = __builtin_amdgcn_mfma_f32_16x16x32_bf16(aP, bV[dt], O[it][dt], 0,0,0);
    }
  }
  #pragma unroll
  for (int it=0; it<2; ++it){
    #pragma unroll
    for (int r=0; r<4; ++r){
      int i = w*32 + it*16 + quad*4 + r;
      int obase = ((b*128 + i)*128 + j)*512 + pass*256 + h*32;
      #pragma unroll
      for (int dt=0; dt<2; ++dt)
        Va[obase + dt*16 + l15] = f2us(O[it][dt][r] * inv[it][r]);
    }
  }
}

// ---------------- Output GEMM: LDS-tiled 128x128, K=512, 2 col groups ----------------
__global__ __launch_bounds__(256) void out_gemm(const u16* __restrict__ Va, const u16* __restrict__ WOt,
                                                const float* __restrict__ bO, float* __restrict__ out){
  __shared__ u16 Asm[128][72];
  __shared__ u16 Bsm[128][72];
  int t = threadIdx.x;
  int g = blockIdx.x >> 8;        // 0..1
  int tmb = blockIdx.x & 255;
  int row0 = tmb*128, col0 = g*128;
  int w = t >> 6, lane = t & 63, quad = lane >> 4, l15 = lane & 15;

  f32x4 zero = {0.f,0.f,0.f,0.f};
  f32x4 acc[2][8];
  #pragma unroll
  for (int mt=0; mt<2; ++mt)
    #pragma unroll
    for (int nt=0; nt<8; ++nt) acc[mt][nt] = zero;

  for (int kc=0; kc<8; ++kc){
    #pragma unroll
    for (int i=0; i<4; ++i){
      int idx = i*256 + t, row = idx>>3, seg = idx&7;
      *(uint4*)&Asm[row][seg*8] = *(const uint4*)(Va + (row0+row)*512 + kc*64 + seg*8);
      *(uint4*)&Bsm[row][seg*8] = *(const uint4*)(WOt + (col0+row)*512 + kc*64 + seg*8);
    }
    __syncthreads();
    #pragma unroll
    for (int s=0; s<2; ++s){
      bf16x8 aF[2], bF[8];
      #pragma unroll
      for (int mt=0; mt<2; ++mt) aF[mt] = *(const bf16x8*)&Asm[w*32 + mt*16 + l15][s*32 + quad*8];
      #pragma unroll
      for (int nt=0; nt<8; ++nt) bF[nt] = *(const bf16x8*)&Bsm[nt*16 + l15][s*32 + quad*8];
      #pragma unroll
      for (int mt=0; mt<2; ++mt)
        #pragma unroll
        for (int nt=0; nt<8; ++nt)
          acc[mt][nt] = __builtin_amdgcn_mfma_f32_16x16x32_bf16(aF[mt], bF[nt], acc[mt][nt], 0,0,0);
    }
    __syncthreads();
  }
  #pragma unroll
  for (int mt=0; mt<2; ++mt){
    #pragma unroll
    for (int nt=0; nt<8; ++nt){
      int col = col0 + nt*16 + l15;
      float bias = bO[col];
      #pragma unroll
      for (int rr=0; rr<4; ++rr){
        int tok = row0 + w*32 + mt*16 + quad*4 + rr;
        out[tok*256 + col] = acc[mt][nt][rr] + bias;
      }
    }
  }
}

// ---------------- ws layout (bytes), total 102,367,232 <= proven 102,400,000 ----------------
#define OFF_ELN   0u            // 16,777,216
#define OFF_QB    16777216u
#define OFF_KB    33554432u
#define OFF_VB    50331648u
#define OFF_VA    67108864u     // 33,554,432 -> 100,663,296
#define OFF_BIASP 100663296u    // 524,288    -> 101,187,584
#define OFF_WTI   101187584u    // 896*256*2 = 458,752 -> 101,646,336
#define OFF_WTO   101646336u    // 458,752   -> 102,105,088
#define OFF_WOT   102105088u    // 262,144   -> 102,367,232

extern "C" void kernel_launch(void* const* d_in, const int* in_sizes, int n_in,
                              void* d_out, int out_size, void* d_ws, size_t ws_size,
                              hipStream_t stream) {
  (void)in_sizes; (void)n_in; (void)out_size; (void)ws_size;
  const float* e        = (const float*)d_in[0];
  const float* mask     = (const float*)d_in[1];
  const float* ln_g     = (const float*)d_in[2];
  const float* ln_b     = (const float*)d_in[3];
  const float* W_qkv_in = (const float*)d_in[4];
  const float* b_qkv_in = (const float*)d_in[5];
  const float* W_E_in   = (const float*)d_in[6];
  const float* b_E_in   = (const float*)d_in[7];
  const float* W_qkv_out= (const float*)d_in[8];
  const float* b_qkv_out= (const float*)d_in[9];
  const float* W_E_out  = (const float*)d_in[10];
  const float* b_E_out  = (const float*)d_in[11];
  const float* W_O      = (const float*)d_in[12];
  const float* b_O      = (const float*)d_in[13];

  char* ws = (char*)d_ws;
  u16*   eln   = (u16*)(ws + OFF_ELN);
  u16*   Qb    = (u16*)(ws + OFF_QB);
  u16*   Kb    = (u16*)(ws + OFF_KB);
  u16*   Vb    = (u16*)(ws + OFF_VB);
  u16*   Va    = (u16*)(ws + OFF_VA);
  u16*   biasP = (u16*)(ws + OFF_BIASP);
  u16*   WtI   = (u16*)(ws + OFF_WTI);
  u16*   WtO   = (u16*)(ws + OFF_WTO);
  u16*   WOt   = (u16*)(ws + OFF_WOT);

  float* out = (float*)d_out;

  hipLaunchKernelGGL(prep_all, dim3(2304), dim3(256), 0, stream,
                     W_qkv_in, W_E_in, W_qkv_out, W_E_out, W_O, WtI, WtO, WOt);
  hipLaunchKernelGGL(ln_kernel, dim3(8192), dim3(256), 0, stream, e, ln_g, ln_b, eln);

  // in pass
  hipLaunchKernelGGL(qkv_gemm, dim3(1792), dim3(256), 0, stream, eln, WtI, b_qkv_in, b_E_in, mask,
                     Qb, Kb, Vb, biasP, 0);
  hipLaunchKernelGGL(attn_mfma, dim3(2048), dim3(256), 0, stream, Qb, Kb, Vb, biasP, Va, 0);

  // out pass
  hipLaunchKernelGGL(qkv_gemm, dim3(1792), dim3(256), 0, stream, eln, WtO, b_qkv_out, b_E_out, mask,
                     Qb, Kb, Vb, biasP, 1);
  hipLaunchKernelGGL(attn_mfma, dim3(2048), dim3(256), 0, stream, Qb, Kb, Vb, biasP, Va, 1);

  hipLaunchKernelGGL(out_gemm, dim3(512), dim3(256), 0, stream, Va, WOt, b_O, out);
}

// Round 14
// 317.836 us; speedup vs baseline: 1.0836x; 1.0836x over previous
//
#include <hip/hip_runtime.h>

// Problem: B=2, N=128, C=256, H=8, D=32. Inputs fp32, OUTPUT fp32 (proven R6).
// R14: GEMM geometry = R12 (128x64, proven best). Staging rewritten with
// __builtin_amdgcn_global_load_lds width=16 (async DMA, no VGPR round-trip).
// Pad is impossible with DMA (wave-uniform base + lane*16), so conflict
// avoidance via XOR swizzle: LDS[row][cc] = global chunk cc^(row&7); readers
// index chunk (s*4+quad)^(l15&7) -> exactly 8 lanes per 4-bank group (b128
// minimum, conflict-free); global side stays line-coalesced (permutation
// within a 128B row segment). Attn/LN/preps = R12.
typedef unsigned short u16;
typedef __attribute__((ext_vector_type(8))) short bf16x8;   // 8 bf16 MFMA A/B frag
typedef __attribute__((ext_vector_type(4))) float f32x4;    // MFMA C/D frag

#define SCALE 0.17677669529663687f  // 32^-0.5

__device__ __forceinline__ float us2f(u16 u){ return __uint_as_float(((unsigned int)u)<<16); }
__device__ __forceinline__ u16 f2us(float f){
  unsigned int x = __float_as_uint(f);
  x += 0x7fffu + ((x>>16)&1u);   // RNE
  return (u16)(x>>16);
}
// async 16B/lane global->LDS (lds base must be wave-uniform)
__device__ __forceinline__ void gl_lds16(const u16* g, u16* l){
  __builtin_amdgcn_global_load_lds(
    (const __attribute__((address_space(1))) unsigned int*)g,
    (__attribute__((address_space(3))) unsigned int*)l, 16, 0, 0);
}

// ---------------- LayerNorm: one wave per token (256 ch), float4 loads ----------------
__global__ __launch_bounds__(256) void ln_kernel(const float* __restrict__ e, const float* __restrict__ g,
                                                 const float* __restrict__ bb, u16* __restrict__ eln){
  int t = threadIdx.x;
  int tok = blockIdx.x*4 + (t>>6);
  int lane = t & 63;
  int c0 = lane*4;
  float4 x = *(const float4*)(e + tok*256 + c0);
  float sum = x.x+x.y+x.z+x.w;
  float sq  = x.x*x.x + x.y*x.y + x.z*x.z + x.w*x.w;
  #pragma unroll
  for (int off=32; off>=1; off>>=1){ sum += __shfl_xor(sum, off); sq += __shfl_xor(sq, off); }
  float mu = sum * 0.00390625f;
  float var = sq * 0.00390625f - mu*mu;
  float rstd = rsqrtf(var + 1e-5f);
  float4 gv = *(const float4*)(g + c0);
  float4 bv = *(const float4*)(bb + c0);
  ushort4 o;
  o.x = f2us((x.x-mu)*rstd*gv.x + bv.x);
  o.y = f2us((x.y-mu)*rstd*gv.y + bv.y);
  o.z = f2us((x.z-mu)*rstd*gv.z + bv.z);
  o.w = f2us((x.w-mu)*rstd*gv.w + bv.w);
  *(ushort4*)(eln + tok*256 + c0) = o;
}

// ---------------- prep_all: Wt_in, Wt_out [832][256] (row n' = sec*256+h*32+d), WOt ----------------
__global__ __launch_bounds__(256) void prep_all(const float* __restrict__ Wi, const float* __restrict__ WEi,
                                                const float* __restrict__ Wo, const float* __restrict__ WEo,
                                                const float* __restrict__ WO,
                                                u16* __restrict__ WtI, u16* __restrict__ WtO,
                                                u16* __restrict__ WOt){
  int idx = blockIdx.x*256 + threadIdx.x;   // 557056 total
  if (idx < 425984){
    int which = idx >= 212992;
    int id2 = which ? idx - 212992 : idx;
    const float* W  = which ? Wo  : Wi;
    const float* WE = which ? WEo : WEi;
    u16* Wt = which ? WtO : WtI;
    int n = id2 >> 8, k = id2 & 255;
    float v;
    if (n < 768){
      int sec = n >> 8, r = n & 255, h = r >> 5, d = r & 31;
      v = W[k*768 + sec*256 + d*8 + h];
    } else if (n < 776) v = WE[k*8 + (n-768)];
    else v = 0.f;
    Wt[id2] = f2us(v);
  } else if (idx < 557056){
    int id2 = idx - 425984;        // WOt[256][512]: k' = pass*256+h*32+d <-> row d*16+pass*8+h
    int n = id2 >> 9, kp = id2 & 511;
    int pass = kp >> 8, h = (kp >> 5) & 7, d = kp & 31;
    int r = d*16 + pass*8 + h;
    WOt[id2] = f2us(WO[r*256 + n]);
  }
}

// ---------------- QKV (+E) GEMM: 128x64 tiles, BK=64, async-DMA swizzled staging ----------------
__global__ __launch_bounds__(256) void qkv_gemm(const u16* __restrict__ eln, const u16* __restrict__ Wt,
    const float* __restrict__ bqkv, const float* __restrict__ bE, const float* __restrict__ mask,
    u16* __restrict__ Qb, u16* __restrict__ Kb, u16* __restrict__ Vb, u16* __restrict__ biasP,
    int pass){
  __shared__ u16 Asm[128*64];   // unpadded; XOR-swizzled content
  __shared__ u16 Bsm[64*64];
  int t = threadIdx.x;
  int g = blockIdx.x >> 8;        // 0..12 col group
  int tmb = blockIdx.x & 255;     // token tile
  int row0 = tmb*128, col0 = g*64;
  int w = t >> 6, lane = t & 63, quad = lane >> 4, l15 = lane & 15;
  int lr = lane >> 3, cc = lane & 7;    // staging: row-in-window, chunk
  int sw8 = (cc ^ lr) << 3;             // swizzled source offset (u16)

  f32x4 zero = {0.f,0.f,0.f,0.f};
  f32x4 acc[2][4];
  #pragma unroll
  for (int mt=0; mt<2; ++mt)
    #pragma unroll
    for (int nt=0; nt<4; ++nt) acc[mt][nt] = zero;

  for (int kc=0; kc<4; ++kc){
    #pragma unroll
    for (int i=0; i<4; ++i){
      int lrow = w*32 + i*8;            // window base (wave-uniform)
      gl_lds16(eln + (row0 + lrow + lr)*256 + kc*64 + sw8, &Asm[lrow*64]);
    }
    #pragma unroll
    for (int j=0; j<2; ++j){
      int brow = w*16 + j*8;
      gl_lds16(Wt + (col0 + brow + lr)*256 + kc*64 + sw8, &Bsm[brow*64]);
    }
    __syncthreads();
    #pragma unroll
    for (int s=0; s<2; ++s){
      bf16x8 aF[2], bF[4];
      #pragma unroll
      for (int mt=0; mt<2; ++mt){
        int row = w*32 + mt*16 + l15;
        aF[mt] = *(const bf16x8*)&Asm[row*64 + ((((s<<2)+quad) ^ (l15&7))<<3)];
      }
      #pragma unroll
      for (int nt=0; nt<4; ++nt){
        int row = nt*16 + l15;
        bF[nt] = *(const bf16x8*)&Bsm[row*64 + ((((s<<2)+quad) ^ (l15&7))<<3)];
      }
      #pragma unroll
      for (int mt=0; mt<2; ++mt)
        #pragma unroll
        for (int nt=0; nt<4; ++nt)
          acc[mt][nt] = __builtin_amdgcn_mfma_f32_16x16x32_bf16(aF[mt], bF[nt], acc[mt][nt], 0,0,0);
    }
    __syncthreads();
  }
  #pragma unroll
  for (int mt=0; mt<2; ++mt){
    #pragma unroll
    for (int nt=0; nt<4; ++nt){
      int col = col0 + nt*16 + l15;      // n' (permuted order)
      #pragma unroll
      for (int rr=0; rr<4; ++rr){
        int tok = row0 + w*32 + mt*16 + quad*4 + rr;
        float v = acc[mt][nt][rr];
        if (col < 768){
          int sec = col >> 8, r = col & 255, h = r >> 5, d = r & 31;
          v += bqkv[sec*256 + d*8 + h];
          int off = tok*256 + r;            // [tok][h][d] directly
          if (sec == 0)      Qb[off] = f2us(v * SCALE);
          else if (sec == 1) Kb[off] = f2us(v);
          else               Vb[off] = f2us(v);
        } else if (col < 776){
          int h = col - 768;
          int bb = tok >> 14, t1 = (tok >> 7) & 127, t2 = tok & 127;
          int tq = pass ? t2 : t1, tk = pass ? t1 : t2;
          float bv2 = v + bE[h] + mask[tok*8 + h];   // mask src == tok*8+h both passes
          biasP[(((bb*8 + h)*128 + tq)*128) + (tk & 15)*8 + (tk >> 4)] = f2us(bv2);
        }
      }
    }
  }
}

// ---------------- MFMA attention: one block per (b,j,h) (R12-proven) ----------------
__global__ __launch_bounds__(256) void attn_mfma(const u16* __restrict__ Qb, const u16* __restrict__ Kb,
    const u16* __restrict__ Vb, const u16* __restrict__ biasP, u16* __restrict__ Va, int pass){
  __shared__ __align__(16) u16 uni[17408];     // union{Qs[128][40]+Ks[128][40], Ps[128][136]}
  __shared__ __align__(16) u16 VsT[32][136];
  typedef u16 row40[40];
  typedef u16 row136[136];
  row40*  Qs = (row40*)uni;
  row40*  Ks = (row40*)(uni + 5120);
  row136* Ps = (row136*)uni;
  int t = threadIdx.x;
  int bx = blockIdx.x;
  int h = bx & 7, j = (bx>>3) & 127, b = bx >> 10;

  #pragma unroll
  for (int it2=0; it2<2; ++it2){
    int idx = it2*256 + t;              // 512 chunks of 8 u16
    int row = idx >> 2, seg = idx & 3;
    int qoff  = ((b*128 + row)*128 + j)*256 + h*32 + seg*8;
    int kvtok = (pass == 0) ? ((b*128 + j)*128 + row) : ((b*128 + row)*128 + j);
    int kvoff = kvtok*256 + h*32 + seg*8;
    *(uint4*)&Qs[row][seg*8] = *(const uint4*)(Qb + qoff);
    *(uint4*)&Ks[row][seg*8] = *(const uint4*)(Kb + kvoff);
    uint4 vv = *(const uint4*)(Vb + kvoff);
    const u16* vp = (const u16*)&vv;
    #pragma unroll
    for (int q=0;q<8;++q) VsT[seg*8+q][row] = vp[q];   // transposed: [d][tok]
  }
  __syncthreads();

  int w = t >> 6, lane = t & 63, quad = lane >> 4, l15 = lane & 15;
  bf16x8 aQ[2];
  #pragma unroll
  for (int it=0; it<2; ++it) aQ[it] = *(const bf16x8*)&Qs[w*32 + it*16 + l15][quad*8];
  f32x4 zero = {0.f,0.f,0.f,0.f};
  f32x4 S[2][8];
  #pragma unroll
  for (int tk=0; tk<8; ++tk){
    bf16x8 bK = *(const bf16x8*)&Ks[tk*16 + l15][quad*8];
    #pragma unroll
    for (int it=0; it<2; ++it)
      S[it][tk] = __builtin_amdgcn_mfma_f32_16x16x32_bf16(aQ[it], bK, zero, 0,0,0);
  }
  __syncthreads();   // Qs/Ks dead before Ps overwrites the union
  const u16* bpP = biasP + ((b*8 + h)*128)*128;
  float inv[2][4];
  #pragma unroll
  for (int it=0; it<2; ++it){
    #pragma unroll
    for (int r=0; r<4; ++r){
      int i = w*32 + it*16 + quad*4 + r;
      uint4 b4 = *(const uint4*)(bpP + i*128 + l15*8);
      const u16* bu = (const u16*)&b4;
      float sv[8];
      #pragma unroll
      for (int tk=0; tk<8; ++tk) sv[tk] = S[it][tk][r] + us2f(bu[tk]);
      float m = sv[0];
      #pragma unroll
      for (int tk=1; tk<8; ++tk) m = fmaxf(m, sv[tk]);
      m = fmaxf(m, __shfl_xor(m,1)); m = fmaxf(m, __shfl_xor(m,2));
      m = fmaxf(m, __shfl_xor(m,4)); m = fmaxf(m, __shfl_xor(m,8));
      float l = 0.f;
      #pragma unroll
      for (int tk=0; tk<8; ++tk){ float p = __expf(sv[tk]-m); sv[tk] = p; l += p; }
      l += __shfl_xor(l,1); l += __shfl_xor(l,2); l += __shfl_xor(l,4); l += __shfl_xor(l,8);
      inv[it][r] = 1.0f / l;
      #pragma unroll
      for (int tk=0; tk<8; ++tk) Ps[i][tk*16 + l15] = f2us(sv[tk]);
    }
  }
  f32x4 O[2][2];
  #pragma unroll
  for (int it=0; it<2; ++it)
    #pragma unroll
    for (int dt=0; dt<2; ++dt) O[it][dt] = zero;
  #pragma unroll
  for (int kc=0; kc<4; ++kc){
    bf16x8 bV[2];
    #pragma unroll
    for (int dt=0; dt<2; ++dt)
      bV[dt] = *(const bf16x8*)&VsT[dt*16 + l15][kc*32 + quad*8];
    #pragma unroll
    for (int it=0; it<2; ++it){
      bf16x8 aP = *(const bf16x8*)&Ps[w*32 + it*16 + l15][kc*32 + quad*8];
      #pragma unroll
      for (int dt=0; dt<2; ++dt)
        O[it][dt] = __builtin_amdgcn_mfma_f32_16x16x32_bf16(aP, bV[dt], O[it][dt], 0,0,0);
    }
  }
  #pragma unroll
  for (int it=0; it<2; ++it){
    #pragma unroll
    for (int r=0; r<4; ++r){
      int i = w*32 + it*16 + quad*4 + r;
      int obase = ((b*128 + i)*128 + j)*512 + pass*256 + h*32;
      #pragma unroll
      for (int dt=0; dt<2; ++dt)
        Va[obase + dt*16 + l15] = f2us(O[it][dt][r] * inv[it][r]);
    }
  }
}

// ---------------- Output GEMM: 128x64 tiles, K=512, async-DMA swizzled staging ----------------
__global__ __launch_bounds__(256) void out_gemm(const u16* __restrict__ Va, const u16* __restrict__ WOt,
                                                const float* __restrict__ bO, float* __restrict__ out){
  __shared__ u16 Asm[128*64];
  __shared__ u16 Bsm[64*64];
  int t = threadIdx.x;
  int g = blockIdx.x >> 8;        // 0..3
  int tmb = blockIdx.x & 255;
  int row0 = tmb*128, col0 = g*64;
  int w = t >> 6, lane = t & 63, quad = lane >> 4, l15 = lane & 15;
  int lr = lane >> 3, cc = lane & 7;
  int sw8 = (cc ^ lr) << 3;

  f32x4 zero = {0.f,0.f,0.f,0.f};
  f32x4 acc[2][4];
  #pragma unroll
  for (int mt=0; mt<2; ++mt)
    #pragma unroll
    for (int nt=0; nt<4; ++nt) acc[mt][nt] = zero;

  for (int kc=0; kc<8; ++kc){
    #pragma unroll
    for (int i=0; i<4; ++i){
      int lrow = w*32 + i*8;
      gl_lds16(Va + (row0 + lrow + lr)*512 + kc*64 + sw8, &Asm[lrow*64]);
    }
    #pragma unroll
    for (int j=0; j<2; ++j){
      int brow = w*16 + j*8;
      gl_lds16(WOt + (col0 + brow + lr)*512 + kc*64 + sw8, &Bsm[brow*64]);
    }
    __syncthreads();
    #pragma unroll
    for (int s=0; s<2; ++s){
      bf16x8 aF[2], bF[4];
      #pragma unroll
      for (int mt=0; mt<2; ++mt){
        int row = w*32 + mt*16 + l15;
        aF[mt] = *(const bf16x8*)&Asm[row*64 + ((((s<<2)+quad) ^ (l15&7))<<3)];
      }
      #pragma unroll
      for (int nt=0; nt<4; ++nt){
        int row = nt*16 + l15;
        bF[nt] = *(const bf16x8*)&Bsm[row*64 + ((((s<<2)+quad) ^ (l15&7))<<3)];
      }
      #pragma unroll
      for (int mt=0; mt<2; ++mt)
        #pragma unroll
        for (int nt=0; nt<4; ++nt)
          acc[mt][nt] = __builtin_amdgcn_mfma_f32_16x16x32_bf16(aF[mt], bF[nt], acc[mt][nt], 0,0,0);
    }
    __syncthreads();
  }
  #pragma unroll
  for (int mt=0; mt<2; ++mt){
    #pragma unroll
    for (int nt=0; nt<4; ++nt){
      int col = col0 + nt*16 + l15;
      float bias = bO[col];
      #pragma unroll
      for (int rr=0; rr<4; ++rr){
        int tok = row0 + w*32 + mt*16 + quad*4 + rr;
        out[tok*256 + col] = acc[mt][nt][rr] + bias;
      }
    }
  }
}

// ---------------- ws layout (bytes), total <= 102,400,000 (proven-safe envelope) ----------------
#define OFF_ELN   0u            // 16,777,216
#define OFF_QB    16777216u
#define OFF_KB    33554432u
#define OFF_VB    50331648u
#define OFF_VA    67108864u     // 33,554,432 -> 100,663,296
#define OFF_BIASP 100663296u    // 524,288    -> 101,187,584
#define OFF_WTI   101187584u    // 425,984    -> 101,613,568
#define OFF_WTO   101613568u    // 425,984    -> 102,039,552
#define OFF_WOT   102039552u    // 262,144    -> 102,301,696

extern "C" void kernel_launch(void* const* d_in, const int* in_sizes, int n_in,
                              void* d_out, int out_size, void* d_ws, size_t ws_size,
                              hipStream_t stream) {
  (void)in_sizes; (void)n_in; (void)out_size; (void)ws_size;
  const float* e        = (const float*)d_in[0];
  const float* mask     = (const float*)d_in[1];
  const float* ln_g     = (const float*)d_in[2];
  const float* ln_b     = (const float*)d_in[3];
  const float* W_qkv_in = (const float*)d_in[4];
  const float* b_qkv_in = (const float*)d_in[5];
  const float* W_E_in   = (const float*)d_in[6];
  const float* b_E_in   = (const float*)d_in[7];
  const float* W_qkv_out= (const float*)d_in[8];
  const float* b_qkv_out= (const float*)d_in[9];
  const float* W_E_out  = (const float*)d_in[10];
  const float* b_E_out  = (const float*)d_in[11];
  const float* W_O      = (const float*)d_in[12];
  const float* b_O      = (const float*)d_in[13];

  char* ws = (char*)d_ws;
  u16*   eln   = (u16*)(ws + OFF_ELN);
  u16*   Qb    = (u16*)(ws + OFF_QB);
  u16*   Kb    = (u16*)(ws + OFF_KB);
  u16*   Vb    = (u16*)(ws + OFF_VB);
  u16*   Va    = (u16*)(ws + OFF_VA);
  u16*   biasP = (u16*)(ws + OFF_BIASP);
  u16*   WtI   = (u16*)(ws + OFF_WTI);
  u16*   WtO   = (u16*)(ws + OFF_WTO);
  u16*   WOt   = (u16*)(ws + OFF_WOT);

  float* out = (float*)d_out;

  hipLaunchKernelGGL(prep_all, dim3(2176), dim3(256), 0, stream,
                     W_qkv_in, W_E_in, W_qkv_out, W_E_out, W_O, WtI, WtO, WOt);
  hipLaunchKernelGGL(ln_kernel, dim3(8192), dim3(256), 0, stream, e, ln_g, ln_b, eln);

  // in pass
  hipLaunchKernelGGL(qkv_gemm, dim3(3328), dim3(256), 0, stream, eln, WtI, b_qkv_in, b_E_in, mask,
                     Qb, Kb, Vb, biasP, 0);
  hipLaunchKernelGGL(attn_mfma, dim3(2048), dim3(256), 0, stream, Qb, Kb, Vb, biasP, Va, 0);

  // out pass
  hipLaunchKernelGGL(qkv_gemm, dim3(3328), dim3(256), 0, stream, eln, WtO, b_qkv_out, b_E_out, mask,
                     Qb, Kb, Vb, biasP, 1);
  hipLaunchKernelGGL(attn_mfma, dim3(2048), dim3(256), 0, stream, Qb, Kb, Vb, biasP, Va, 1);

  hipLaunchKernelGGL(out_gemm, dim3(1024), dim3(256), 0, stream, Va, WOt, b_O, out);
}